// Round 3
// baseline (284.170 us; speedup 1.0000x reference)
//
#include <hip/hip_runtime.h>

// MIND-SSC loss, N=2, C=1, D=H=W=128, radius=1, dilation=2.
// Round 9: vectorized window staging in the heavy kernel.
//  - stage_pair: interior threads (3<=gx<=123, identity clamps) load 6
//    dwordx4 column-windows per image (12 VMEM) instead of 36 scalar
//    gathers; taps become vector components. Channel math is
//    statement-identical to round 8 (bit-exact).
//  - edge threads keep the exact double-clamp scalar path.
//  - graph stays 3 nodes: memset / fused / combo (round-8 structure).

#define DIM 128
#define HW (128 * 128)
#define DHW (128 * 128 * 128)
#define NVOX (2 * DHW)
#define LOSS_COUNT (2.0 * 12.0 * DHW)
#define TOTAL_BLOCKS 1024u

#define TS   16                   // tile side (y and x)
#define SY   18                   // xsum rows incl. y halo
#define NSP  (SY * TS)            // 288 xsum positions
#define CHZ  16                   // z-chunk per block
#define PSTR 7                    // f4 stride per position (6 used + 1 pad)

typedef float f4 __attribute__((ext_vector_type(4)));
typedef float f2 __attribute__((ext_vector_type(2)));
typedef float f4a __attribute__((ext_vector_type(4), aligned(4)));

__device__ __forceinline__ int clampi(int v) {
    v = v < 0 ? 0 : v;
    return v > 127 ? 127 : v;
}

__device__ __forceinline__ unsigned fkey(float f) {
    unsigned u = __float_as_uint(f);
    return (u & 0x80000000u) ? ~u : (u | 0x80000000u);
}
__device__ __forceinline__ float fdec(unsigned k) {
    unsigned u = (k & 0x80000000u) ? (k ^ 0x80000000u) : ~k;
    return __uint_as_float(u);
}

__device__ __forceinline__ void block_reduce_atomic(float v, double* dst) {
#pragma unroll
    for (int off = 32; off > 0; off >>= 1)
        v += __shfl_down(v, off, 64);
    __shared__ float red[4];
    int lane = threadIdx.x & 63;
    int wid  = threadIdx.x >> 6;
    if (lane == 0) red[wid] = v;
    __syncthreads();
    if (threadIdx.x == 0) {
        double t = (double)red[0] + (double)red[1] + (double)red[2] + (double)red[3];
        atomicAdd(dst, t);
    }
    __syncthreads();
}

// min stored inverted: max over ~fkey(v)  <=>  min over v. Identity is 0 for
// all four reductions, so a single memset(0) initializes the workspace.
__device__ __forceinline__ void block_minmax_atomic(float mnp, float mxp,
                                                    float mnt, float mxt,
                                                    unsigned* keys) {
#pragma unroll
    for (int off = 32; off > 0; off >>= 1) {
        mnp = fminf(mnp, __shfl_down(mnp, off, 64));
        mxp = fmaxf(mxp, __shfl_down(mxp, off, 64));
        mnt = fminf(mnt, __shfl_down(mnt, off, 64));
        mxt = fmaxf(mxt, __shfl_down(mxt, off, 64));
    }
    __shared__ float r[4][4];
    int lane = threadIdx.x & 63, wid = threadIdx.x >> 6;
    if (lane == 0) { r[wid][0] = mnp; r[wid][1] = mxp; r[wid][2] = mnt; r[wid][3] = mxt; }
    __syncthreads();
    if (threadIdx.x == 0) {
        float a = fminf(fminf(r[0][0], r[1][0]), fminf(r[2][0], r[3][0]));
        float b = fmaxf(fmaxf(r[0][1], r[1][1]), fmaxf(r[2][1], r[3][1]));
        float c = fminf(fminf(r[0][2], r[1][2]), fminf(r[2][2], r[3][2]));
        float d = fmaxf(fmaxf(r[0][3], r[1][3]), fmaxf(r[2][3], r[3][3]));
        atomicMax(&keys[0], ~fkey(a));   // min pred-var
        atomicMax(&keys[1], fkey(b));    // max pred-var
        atomicMax(&keys[2], ~fkey(c));   // min targ-var
        atomicMax(&keys[3], fkey(d));    // max targ-var
    }
    __syncthreads();
}

// Per-thread staging descriptor: one xsum position (px in [0,16), py in [0,18)).
struct SPos {
    int y0, ym, yp;          // row offsets * DIM: gy, clamp(gy-2), clamp(gy+2)
    int cx[3], cm[3], cp[3]; // per-wx tap columns: c, clamp(c-2), clamp(c+2)
    int woff;                // f4 index of this position's quads
    int gx;                  // raw global x of this position
    bool interior;           // all column clamps are identity AND no OOB loads
};

__device__ __forceinline__ SPos make_spos(int p, int y0t, int x0t, int stride) {
    SPos q;
    int py = p >> 4, px = p & 15;
    int gy = clampi(y0t - 1 + py);
    int gx = x0t + px;
    q.y0 = gy * DIM; q.ym = clampi(gy - 2) * DIM; q.yp = clampi(gy + 2) * DIM;
#pragma unroll
    for (int wx = 0; wx < 3; ++wx) {
        int c = clampi(gx + wx - 1);   // box tap clamp (outer pad)
        q.cx[wx] = c;
        q.cm[wx] = clampi(c - 2);      // dilation clamp (inner pad)
        q.cp[wx] = clampi(c + 2);
    }
    q.woff = p * stride;
    q.gx = gx;
    // gx>=3: cols gx-3..gx+3 unclamped; gx<=123: window load gx+1..gx+4 stays
    // inside the buffer even at the last row/plane (col 128 never touched).
    q.interior = (gx >= 3) && (gx <= 123);
    return q;
}

// ---------------- fused pass (packed pred/targ) ----------------

__device__ __forceinline__ void acc12(f2 acc[12], f2 s0, f2 s1, f2 s2,
                                      f2 s3, f2 s4, f2 s5) {
    f2 d;
    d = s1 - s0; acc[0]  += d * d;
    d = s2 - s0; acc[1]  += d * d;
    d = s2 - s1; acc[2]  += d * d;
    d = s3 - s0; acc[3]  += d * d;
    d = s3 - s2; acc[4]  += d * d;
    d = s4 - s1; acc[5]  += d * d;
    d = s4 - s2; acc[6]  += d * d;
    d = s4 - s3; acc[7]  += d * d;
    d = s5 - s0; acc[8]  += d * d;
    d = s5 - s1; acc[9]  += d * d;
    d = s5 - s3; acc[10] += d * d;
    d = s5 - s4; acc[11] += d * d;
}

__device__ __forceinline__ f4a ld4(const float* p) {
    return *(const f4a*)p;
}

__device__ __forceinline__ void stage_pair(const float* __restrict__ ip,
                                           const float* __restrict__ tp,
                                           int zm, int zc, int zp,
                                           const SPos& q, f4* __restrict__ X) {
    f2 acc[12];
#pragma unroll
    for (int c = 0; c < 12; ++c) acc[c] = (f2)0.0f;

    if (q.interior) {
        // 6 column-window loads per image; taps = vector components.
        // tap columns: s0/s2/s4/s5: gx-1..gx+1, s1: gx-3..gx-1, s3: gx+1..gx+3
        const int gx = q.gx;
        const int o0 = zm + q.y0 + gx - 1;   // s0 window
        const int o1 = zc + q.y0 + gx - 3;   // s1 window
        const int o3 = zc + q.y0 + gx + 1;   // s3 window
        const int o2 = zc + q.ym + gx - 1;   // s2 window
        const int o5 = zc + q.yp + gx - 1;   // s5 window
        const int o4 = zp + q.y0 + gx - 1;   // s4 window
        f4a P0 = ld4(ip + o0), T0 = ld4(tp + o0);
        f4a P1 = ld4(ip + o1), T1 = ld4(tp + o1);
        f4a P3 = ld4(ip + o3), T3 = ld4(tp + o3);
        f4a P2 = ld4(ip + o2), T2 = ld4(tp + o2);
        f4a P5 = ld4(ip + o5), T5 = ld4(tp + o5);
        f4a P4 = ld4(ip + o4), T4 = ld4(tp + o4);
#pragma unroll
        for (int wx = 0; wx < 3; ++wx) {
            f2 s0 = {P0[wx], T0[wx]};
            f2 s1 = {P1[wx], T1[wx]};
            f2 s2 = {P2[wx], T2[wx]};
            f2 s3 = {P3[wx], T3[wx]};
            f2 s4 = {P4[wx], T4[wx]};
            f2 s5 = {P5[wx], T5[wx]};
            acc12(acc, s0, s1, s2, s3, s4, s5);
        }
    } else {
        // exact double-clamp scalar path (edge columns only)
#pragma unroll
        for (int wx = 0; wx < 3; ++wx) {
            int o0 = zm + q.y0 + q.cx[wx];
            int o1 = zc + q.y0 + q.cm[wx];
            int o2 = zc + q.ym + q.cx[wx];
            int o3 = zc + q.y0 + q.cp[wx];
            int o4 = zp + q.y0 + q.cx[wx];
            int o5 = zc + q.yp + q.cx[wx];
            f2 s0 = {ip[o0], tp[o0]};
            f2 s1 = {ip[o1], tp[o1]};
            f2 s2 = {ip[o2], tp[o2]};
            f2 s3 = {ip[o3], tp[o3]};
            f2 s4 = {ip[o4], tp[o4]};
            f2 s5 = {ip[o5], tp[o5]};
            acc12(acc, s0, s1, s2, s3, s4, s5);
        }
    }
#pragma unroll
    for (int k = 0; k < 6; ++k) {
        f4 w;
        w.x = acc[2 * k].x;     w.y = acc[2 * k].y;
        w.z = acc[2 * k + 1].x; w.w = acc[2 * k + 1].y;
        X[q.woff + k] = w;
    }
}

__device__ __forceinline__ void box3y_pair(const f4* __restrict__ X,
                                           int ty, int tx, f4 q[6]) {
    int b0 = ((ty + 0) * TS + tx) * PSTR;
    int b1 = ((ty + 1) * TS + tx) * PSTR;
    int b2 = ((ty + 2) * TS + tx) * PSTR;
#pragma unroll
    for (int k = 0; k < 6; ++k)
        q[k] = X[b0 + k] + X[b1 + k] + X[b2 + k];
}

__global__ __launch_bounds__(256, 4) void fused_kernel(const float* __restrict__ pred,
                                                       const float* __restrict__ targ,
                                                       double* __restrict__ acc,
                                                       unsigned* __restrict__ keys) {
    __shared__ f4 X[NSP * PSTR];
    const int t = threadIdx.x;
    const int tile = blockIdx.x & 63, n = blockIdx.x >> 6;
    const int x0t = (tile & 7) * TS, y0t = (tile >> 3) * TS;
    const int z0 = blockIdx.y * CHZ;
    const float* ip = pred + (size_t)n * DHW;
    const float* tp = targ + (size_t)n * DHW;

    SPos pa = make_spos(t, y0t, x0t, PSTR);
    const bool hasB = (t + 256) < NSP;
    SPos pb = make_spos(hasB ? (t + 256) : 0, y0t, x0t, PSTR);

    const int ty = t >> 4, tx = t & 15;

    f4 A[6], B[6];
#pragma unroll
    for (int k = 0; k < 6; ++k) { A[k] = (f4)0.0f; B[k] = (f4)0.0f; }

    float vsump = 0.0f, vsumt = 0.0f, lsum = 0.0f;
    float locmnp = 1e30f, locmxp = -1e30f, locmnt = 1e30f, locmxt = -1e30f;

    for (int tz = z0 - 1; tz <= z0 + CHZ; ++tz) {
        int zq = clampi(tz);
        int zc = zq * HW, zm = clampi(zq - 2) * HW, zp = clampi(zq + 2) * HW;
        stage_pair(ip, tp, zm, zc, zp, pa, X);
        if (hasB) stage_pair(ip, tp, zm, zc, zp, pb, X);
        __syncthreads();

        f4 q[6];
        box3y_pair(X, ty, tx, q);
        __syncthreads();

        int ze = tz - 1;
        if (ze >= z0) {
            f4 v[6];
#pragma unroll
            for (int k = 0; k < 6; ++k) v[k] = A[k] + q[k];

            float mnp = v[0][0], mnt = v[0][1];
            float smp = 0.0f, smt = 0.0f;
#pragma unroll
            for (int c = 0; c < 12; ++c) {
                float pv = v[c >> 1][(c & 1) * 2];
                float tv = v[c >> 1][(c & 1) * 2 + 1];
                mnp = fminf(mnp, pv); smp += pv;
                mnt = fminf(mnt, tv); smt += tv;
            }
            float varp = smp * (1.0f / 12.0f) - mnp;
            float vart = smt * (1.0f / 12.0f) - mnt;
            vsump += varp; vsumt += vart;
            locmnp = fminf(locmnp, varp); locmxp = fmaxf(locmxp, varp);
            locmnt = fminf(locmnt, vart); locmxt = fmaxf(locmxt, vart);

            float invp = -1.0f / varp;   // UNCLIPPED (validated by combo kernel)
            float invt = -1.0f / vart;
            float la = 0.0f;
#pragma unroll
            for (int c = 0; c < 12; ++c) {
                float pv = v[c >> 1][(c & 1) * 2];
                float tv = v[c >> 1][(c & 1) * 2 + 1];
                float ep = __expf((pv - mnp) * invp);
                float et = __expf((tv - mnt) * invt);
                float dd = ep - et;
                la += dd * dd;
            }
            lsum += la;
        }
#pragma unroll
        for (int k = 0; k < 6; ++k) { A[k] = B[k] + q[k]; B[k] = q[k]; }
    }

    block_reduce_atomic(vsump, &acc[0]);
    block_reduce_atomic(vsumt, &acc[1]);
    block_reduce_atomic(lsum,  &acc[2]);
    block_minmax_atomic(locmnp, locmxp, locmnt, locmxt, keys);
}

// ---------------- combo: flag + (fallback recompute) + finalize ----------------

__device__ __forceinline__ void stage_xsum(const float* __restrict__ im,
                                           int zm, int zc, int zp,
                                           const SPos& q, f4* __restrict__ P) {
    f4 a = (f4)0.0f, b = (f4)0.0f, c = (f4)0.0f;
#pragma unroll
    for (int wx = 0; wx < 3; ++wx) {
        float s0 = im[zm + q.y0 + q.cx[wx]];
        float s1 = im[zc + q.y0 + q.cm[wx]];
        float s2 = im[zc + q.ym + q.cx[wx]];
        float s3 = im[zc + q.y0 + q.cp[wx]];
        float s4 = im[zp + q.y0 + q.cx[wx]];
        float s5 = im[zc + q.yp + q.cx[wx]];
        float d;
        d = s1 - s0; a.x += d * d;
        d = s2 - s0; a.y += d * d;
        d = s2 - s1; a.z += d * d;
        d = s3 - s0; a.w += d * d;
        d = s3 - s2; b.x += d * d;
        d = s4 - s1; b.y += d * d;
        d = s4 - s2; b.z += d * d;
        d = s4 - s3; b.w += d * d;
        d = s5 - s0; c.x += d * d;
        d = s5 - s1; c.y += d * d;
        d = s5 - s3; c.z += d * d;
        d = s5 - s4; c.w += d * d;
    }
    P[q.woff + 0] = a;
    P[q.woff + 1] = b;
    P[q.woff + 2] = c;
}

__device__ __forceinline__ void box3y(const f4* __restrict__ P,
                                      int ty, int tx, f4 q[3]) {
    int base = (ty * TS + tx) * 3;
#pragma unroll
    for (int k = 0; k < 3; ++k)
        q[k] = P[base + k] + P[base + TS * 3 + k] + P[base + 2 * TS * 3 + k];
}

__device__ __forceinline__ float min12(const f4 v[3]) {
    float mn = v[0][0];
#pragma unroll
    for (int i = 0; i < 4; ++i)
        mn = fminf(mn, fminf(v[0][i], fminf(v[1][i], v[2][i])));
    return mn;
}
__device__ __forceinline__ float sum12(const f4 v[3]) {
    float sm = 0.0f;
#pragma unroll
    for (int i = 0; i < 4; ++i)
        sm += v[0][i] + v[1][i] + v[2][i];
    return sm;
}

__global__ __launch_bounds__(256, 4) void combo_kernel(const float* __restrict__ pred,
                                                       const float* __restrict__ targ,
                                                       double* __restrict__ acc,
                                                       unsigned* __restrict__ keys,
                                                       float* __restrict__ out) {
    // Every block redundantly computes the clip flag from 7 uniform scalars.
    // acc/keys were written by fused_kernel; kernel-boundary ordering makes
    // them visible without fences.
    const float m_p = (float)(acc[0] * (1.0 / (double)NVOX));
    const float m_t = (float)(acc[1] * (1.0 / (double)NVOX));
    const float mnp = fdec(~keys[0]), mxp = fdec(keys[1]);
    const float mnt = fdec(~keys[2]), mxt = fdec(keys[3]);
    // clip leaves v unchanged iff lo <= v <= hi (same fp exprs as fallback path)
    const bool clean = (mnp >= m_p * 0.001f) && (mxp <= m_p * 1000.0f) &&
                       (mnt >= m_t * 0.001f) && (mxt <= m_t * 1000.0f);
    if (clean) {
        if (blockIdx.x == 0 && blockIdx.y == 0 && threadIdx.x == 0)
            out[0] = (float)(acc[2] * (1.0 / LOSS_COUNT));
        return;   // block-uniform exit (~5us for the whole grid)
    }

    // ---- dirty path: full clipped recompute (never taken for these inputs) ----
    __shared__ f4 Xp[NSP * 3];
    __shared__ f4 Xt[NSP * 3];
    const int t = threadIdx.x;
    const int tile = blockIdx.x & 63, n = blockIdx.x >> 6;
    const int x0t = (tile & 7) * TS, y0t = (tile >> 3) * TS;
    const int z0 = blockIdx.y * CHZ;
    const float* ip = pred + (size_t)n * DHW;
    const float* tp = targ + (size_t)n * DHW;

    SPos pa = make_spos(t, y0t, x0t, 3);
    const bool hasB = (t + 256) < NSP;
    SPos pb = make_spos(hasB ? (t + 256) : 0, y0t, x0t, 3);

    const int ty = t >> 4, tx = t & 15;

    f4 Ap[3], Bp[3], At[3], Bt[3];
#pragma unroll
    for (int q = 0; q < 3; ++q) {
        Ap[q] = (f4)0.0f; Bp[q] = (f4)0.0f;
        At[q] = (f4)0.0f; Bt[q] = (f4)0.0f;
    }
    float lsum = 0.0f;

    for (int tz = z0 - 1; tz <= z0 + CHZ; ++tz) {
        int zq = clampi(tz);
        int zc = zq * HW, zm = clampi(zq - 2) * HW, zp = clampi(zq + 2) * HW;
        stage_xsum(ip, zm, zc, zp, pa, Xp);
        stage_xsum(tp, zm, zc, zp, pa, Xt);
        if (hasB) {
            stage_xsum(ip, zm, zc, zp, pb, Xp);
            stage_xsum(tp, zm, zc, zp, pb, Xt);
        }
        __syncthreads();

        f4 qp[3], qt[3];
        box3y(Xp, ty, tx, qp);
        box3y(Xt, ty, tx, qt);
        __syncthreads();

        int ze = tz - 1;
        if (ze >= z0) {
            f4 vp[3], vt[3];
#pragma unroll
            for (int q = 0; q < 3; ++q) {
                vp[q] = Ap[q] + qp[q];
                vt[q] = At[q] + qt[q];
            }
            float mnpv = min12(vp), smp = sum12(vp);
            float mntv = min12(vt), smt = sum12(vt);
            float varp = smp * (1.0f / 12.0f) - mnpv;
            varp = fminf(fmaxf(varp, m_p * 0.001f), m_p * 1000.0f);
            float invp = -1.0f / varp;
            float vart = smt * (1.0f / 12.0f) - mntv;
            vart = fminf(fmaxf(vart, m_t * 0.001f), m_t * 1000.0f);
            float invt = -1.0f / vart;

            float a = 0.0f;
#pragma unroll
            for (int q = 0; q < 3; ++q)
#pragma unroll
                for (int i = 0; i < 4; ++i) {
                    float ep = __expf((vp[q][i] - mnpv) * invp);
                    float et = __expf((vt[q][i] - mntv) * invt);
                    float dd = ep - et;
                    a += dd * dd;
                }
            lsum += a;
        }
#pragma unroll
        for (int q = 0; q < 3; ++q) {
            Ap[q] = Bp[q] + qp[q]; Bp[q] = qp[q];
            At[q] = Bt[q] + qt[q]; Bt[q] = qt[q];
        }
    }

    block_reduce_atomic(lsum, &acc[3]);

    // Fence lives ONLY on the never-taken dirty path.
    __threadfence();
    if (threadIdx.x == 0) {
        unsigned old = atomicAdd(&keys[6], 1u);
        if (old == TOTAL_BLOCKS - 1u) {
            __threadfence();
            double v = atomicAdd(&acc[3], 0.0);
            out[0] = (float)(v * (1.0 / LOSS_COUNT));
        }
    }
}

extern "C" void kernel_launch(void* const* d_in, const int* in_sizes, int n_in,
                              void* d_out, int out_size, void* d_ws, size_t ws_size,
                              hipStream_t stream) {
    const float* pred = (const float*)d_in[0];
    const float* targ = (const float*)d_in[1];
    float* out = (float*)d_out;
    double* acc = (double*)d_ws;                    // [0]=vsum_p [1]=vsum_t [2]=loss_unclip [3]=loss_clip
    unsigned* keys = (unsigned*)((char*)d_ws + 64); // [0..3]=inv-min/max keys, [6]=fallback ctr

    dim3 block(256);
    dim3 grid(128, 8);   // 64 tiles * 2 batch, 8 z-chunks of 16

    hipMemsetAsync(d_ws, 0, 256, stream);  // all-zero init (inverted min keys)
    fused_kernel<<<grid, block, 0, stream>>>(pred, targ, acc, keys);
    combo_kernel<<<grid, block, 0, stream>>>(pred, targ, acc, keys, out);
}

// Round 4
// 222.807 us; speedup vs baseline: 1.2754x; 1.2754x over previous
//
#include <hip/hip_runtime.h>

// MIND-SSC loss, N=2, C=1, D=H=W=128, radius=1, dilation=2.
// Round 10: center-plane LDS staging (cooperative), round-8 graph.
//  - R[2 slots][2 img][22 rows][24 cols] in LDS holds the CENTER z-plane
//    (double-buffered by z parity, staged one iter ahead, ~4 coalesced
//    loads/thread/iter). Taps s1,s2,s3,s5 (24 of 36) become ds_read_b32.
//  - s0/s4 (planes z+-2) stay exact scalar global loads.
//  - Single-clamp staging == nested reference clamps EVERYWHERE except 4
//    proven corner cases (upper-edge ym, lower-edge yp, s1@x-top corner,
//    s3@x-bottom corner) which use exact predicated global loads.
//  - acc12 order unchanged -> bit-exact vs round 8.
//  - R9 lesson: no per-thread vector windows (spill alarm = WRITE_SIZE).

#define DIM 128
#define HW (128 * 128)
#define DHW (128 * 128 * 128)
#define NVOX (2 * DHW)
#define LOSS_COUNT (2.0 * 12.0 * DHW)
#define TOTAL_BLOCKS 1024u

#define TS   16                   // tile side (y and x)
#define SY   18                   // xsum rows incl. y halo
#define NSP  (SY * TS)            // 288 xsum positions
#define CHZ  16                   // z-chunk per block
#define PSTR 7                    // f4 stride per position (6 used + 1 pad)

#define RSTR  24                  // raw row stride (22 used + 2 pad)
#define RROWS 22                  // raw rows  (y0t-3 .. y0t+18)
#define RIMG  (RROWS * RSTR)      // 528 floats per image
#define RSLOT (2 * RIMG)          // 1056 floats per slot
#define RITEMS (2 * RIMG)         // 1056 elements staged per iter

typedef float f4 __attribute__((ext_vector_type(4)));
typedef float f2 __attribute__((ext_vector_type(2)));

__device__ __forceinline__ int clampi(int v) {
    v = v < 0 ? 0 : v;
    return v > 127 ? 127 : v;
}

__device__ __forceinline__ unsigned fkey(float f) {
    unsigned u = __float_as_uint(f);
    return (u & 0x80000000u) ? ~u : (u | 0x80000000u);
}
__device__ __forceinline__ float fdec(unsigned k) {
    unsigned u = (k & 0x80000000u) ? (k ^ 0x80000000u) : ~k;
    return __uint_as_float(u);
}

__device__ __forceinline__ void block_reduce_atomic(float v, double* dst) {
#pragma unroll
    for (int off = 32; off > 0; off >>= 1)
        v += __shfl_down(v, off, 64);
    __shared__ float red[4];
    int lane = threadIdx.x & 63;
    int wid  = threadIdx.x >> 6;
    if (lane == 0) red[wid] = v;
    __syncthreads();
    if (threadIdx.x == 0) {
        double t = (double)red[0] + (double)red[1] + (double)red[2] + (double)red[3];
        atomicAdd(dst, t);
    }
    __syncthreads();
}

// min stored inverted: max over ~fkey(v)  <=>  min over v. Identity is 0 for
// all four reductions, so a single memset(0) initializes the workspace.
__device__ __forceinline__ void block_minmax_atomic(float mnp, float mxp,
                                                    float mnt, float mxt,
                                                    unsigned* keys) {
#pragma unroll
    for (int off = 32; off > 0; off >>= 1) {
        mnp = fminf(mnp, __shfl_down(mnp, off, 64));
        mxp = fmaxf(mxp, __shfl_down(mxp, off, 64));
        mnt = fminf(mnt, __shfl_down(mnt, off, 64));
        mxt = fmaxf(mxt, __shfl_down(mxt, off, 64));
    }
    __shared__ float r[4][4];
    int lane = threadIdx.x & 63, wid = threadIdx.x >> 6;
    if (lane == 0) { r[wid][0] = mnp; r[wid][1] = mxp; r[wid][2] = mnt; r[wid][3] = mxt; }
    __syncthreads();
    if (threadIdx.x == 0) {
        float a = fminf(fminf(r[0][0], r[1][0]), fminf(r[2][0], r[3][0]));
        float b = fmaxf(fmaxf(r[0][1], r[1][1]), fmaxf(r[2][1], r[3][1]));
        float c = fminf(fminf(r[0][2], r[1][2]), fminf(r[2][2], r[3][2]));
        float d = fmaxf(fmaxf(r[0][3], r[1][3]), fmaxf(r[2][3], r[3][3]));
        atomicMax(&keys[0], ~fkey(a));   // min pred-var
        atomicMax(&keys[1], fkey(b));    // max pred-var
        atomicMax(&keys[2], ~fkey(c));   // min targ-var
        atomicMax(&keys[3], fkey(d));    // max targ-var
    }
    __syncthreads();
}

// ---------------- heavy-kernel position descriptor ----------------

struct SPosF {
    int y0, ym, yp;   // global row offsets * DIM
    int cx0, cx1, cx2;// clamped center cols (s0/s4 + exception paths)
    int cm2, cp0;     // corner-exception cols: s1@wx2, s3@wx0
    int woff;         // X f4 offset
    int l_y0;         // LDS word base (img0): (py+2)*RSTR + tx; ym=-2*RSTR, yp=+2*RSTR
    bool exc_ym, exc_yp, exc_s1, exc_s3;
};

__device__ __forceinline__ SPosF make_sposf(int p, int y0t, int x0t) {
    SPosF q;
    int py = p >> 4, tx = p & 15;
    int gy = clampi(y0t - 1 + py);
    int gx = x0t + tx;
    q.y0 = gy * DIM; q.ym = clampi(gy - 2) * DIM; q.yp = clampi(gy + 2) * DIM;
    q.cx0 = clampi(gx - 1);
    q.cx1 = gx;                    // always in [0,127]
    q.cx2 = clampi(gx + 1);
    q.cm2 = clampi(q.cx2 - 2);
    q.cp0 = clampi(q.cx0 + 2);
    q.woff = p * PSTR;
    q.l_y0 = (py + 2) * RSTR + tx;
    q.exc_ym = (y0t == 112) && (py == 17);  // upper-edge ym row
    q.exc_yp = (y0t == 0)   && (py == 0);   // lower-edge yp row
    q.exc_s1 = (x0t == 112) && (tx == 15);  // s1 @ wx=2 corner
    q.exc_s3 = (x0t == 0)   && (tx == 0);   // s3 @ wx=0 corner
    return q;
}

// ---------------- fused pass (packed pred/targ) ----------------

__device__ __forceinline__ void acc12(f2 acc[12], f2 s0, f2 s1, f2 s2,
                                      f2 s3, f2 s4, f2 s5) {
    f2 d;
    d = s1 - s0; acc[0]  += d * d;
    d = s2 - s0; acc[1]  += d * d;
    d = s2 - s1; acc[2]  += d * d;
    d = s3 - s0; acc[3]  += d * d;
    d = s3 - s2; acc[4]  += d * d;
    d = s4 - s1; acc[5]  += d * d;
    d = s4 - s2; acc[6]  += d * d;
    d = s4 - s3; acc[7]  += d * d;
    d = s5 - s0; acc[8]  += d * d;
    d = s5 - s1; acc[9]  += d * d;
    d = s5 - s3; acc[10] += d * d;
    d = s5 - s4; acc[11] += d * d;
}

__device__ __forceinline__ void stage_pair(const float* __restrict__ ip,
                                           const float* __restrict__ tp,
                                           int zm, int zc, int zp,
                                           const float* Rc,  // slot base (img0)
                                           const SPosF& q, f4* __restrict__ X) {
    f2 acc[12];
#pragma unroll
    for (int c = 0; c < 12; ++c) acc[c] = (f2)0.0f;

    const int ly0 = q.l_y0;
    const int lym = q.l_y0 - 2 * RSTR;
    const int lyp = q.l_y0 + 2 * RSTR;
#pragma unroll
    for (int wx = 0; wx < 3; ++wx) {
        const int cxw = (wx == 0) ? q.cx0 : (wx == 1 ? q.cx1 : q.cx2);
        int o0 = zm + q.y0 + cxw;
        int o4 = zp + q.y0 + cxw;
        f2 s0 = {ip[o0], tp[o0]};
        f2 s4 = {ip[o4], tp[o4]};
        f2 s1 = {Rc[ly0 + wx],         Rc[RIMG + ly0 + wx]};
        f2 s3 = {Rc[ly0 + 4 + wx],     Rc[RIMG + ly0 + 4 + wx]};
        f2 s2 = {Rc[lym + 2 + wx],     Rc[RIMG + lym + 2 + wx]};
        f2 s5 = {Rc[lyp + 2 + wx],     Rc[RIMG + lyp + 2 + wx]};
        if (wx == 2 && q.exc_s1) { int o = zc + q.y0 + q.cm2; s1 = {ip[o], tp[o]}; }
        if (wx == 0 && q.exc_s3) { int o = zc + q.y0 + q.cp0; s3 = {ip[o], tp[o]}; }
        if (q.exc_ym)            { int o = zc + q.ym + cxw;   s2 = {ip[o], tp[o]}; }
        if (q.exc_yp)            { int o = zc + q.yp + cxw;   s5 = {ip[o], tp[o]}; }
        acc12(acc, s0, s1, s2, s3, s4, s5);
    }
#pragma unroll
    for (int k = 0; k < 6; ++k) {
        f4 w;
        w.x = acc[2 * k].x;     w.y = acc[2 * k].y;
        w.z = acc[2 * k + 1].x; w.w = acc[2 * k + 1].y;
        X[q.woff + k] = w;
    }
}

__device__ __forceinline__ void box3y_pair(const f4* __restrict__ X,
                                           int ty, int tx, f4 q[6]) {
    int b0 = ((ty + 0) * TS + tx) * PSTR;
    int b1 = ((ty + 1) * TS + tx) * PSTR;
    int b2 = ((ty + 2) * TS + tx) * PSTR;
#pragma unroll
    for (int k = 0; k < 6; ++k)
        q[k] = X[b0 + k] + X[b1 + k] + X[b2 + k];
}

__global__ __launch_bounds__(256, 4) void fused_kernel(const float* __restrict__ pred,
                                                       const float* __restrict__ targ,
                                                       double* __restrict__ acc,
                                                       unsigned* __restrict__ keys) {
    __shared__ f4 X[NSP * PSTR];          // 32256 B
    __shared__ float R[2 * RSLOT];        //  8448 B (2 z-parity slots)
    const int t = threadIdx.x;
    const int tile = blockIdx.x & 63, n = blockIdx.x >> 6;
    const int x0t = (tile & 7) * TS, y0t = (tile >> 3) * TS;
    const int z0 = blockIdx.y * CHZ;
    const float* ip = pred + (size_t)n * DHW;
    const float* tp = targ + (size_t)n * DHW;

    SPosF pa = make_sposf(t, y0t, x0t);
    const bool hasB = (t + 256) < NSP;
    SPosF pb = make_sposf(hasB ? (t + 256) : 0, y0t, x0t);

    // staging descriptors: RITEMS=1056 elements, thread t handles t+j*256
    int sdst[5], ssrc[5]; bool simg[5];
#pragma unroll
    for (int j = 0; j < 5; ++j) {
        int idx = t + j * 256;
        if (idx < RITEMS) {
            int img = idx >= RIMG;
            int e = idx - img * RIMG;
            int r = e / RSTR, c = e - r * RSTR;
            sdst[j] = img * RIMG + e;
            ssrc[j] = clampi(y0t - 3 + r) * DIM + clampi(x0t - 3 + c);
            simg[j] = (img != 0);
        } else sdst[j] = -1;
    }

    const int ty = t >> 4, tx = t & 15;

    f4 A[6], B[6];
#pragma unroll
    for (int k = 0; k < 6; ++k) { A[k] = (f4)0.0f; B[k] = (f4)0.0f; }

    float vsump = 0.0f, vsumt = 0.0f, lsum = 0.0f;
    float locmnp = 1e30f, locmxp = -1e30f, locmnt = 1e30f, locmxt = -1e30f;

    // prologue: stage center plane for first iter (tz = z0-1)
    {
        int pzHW = clampi(z0 - 1) * HW;
        float* Rs = R + ((unsigned)(z0 - 1) & 1u) * RSLOT;
#pragma unroll
        for (int j = 0; j < 5; ++j)
            if (sdst[j] >= 0) Rs[sdst[j]] = (simg[j] ? tp : ip)[pzHW + ssrc[j]];
    }
    __syncthreads();

    for (int tz = z0 - 1; tz <= z0 + CHZ; ++tz) {
        int zq = clampi(tz);
        int zc = zq * HW, zm = clampi(zq - 2) * HW, zp = clampi(zq + 2) * HW;
        int slot = tz & 1;

        // stage NEXT center plane into the other slot (overlaps tap compute)
        if (tz < z0 + CHZ) {
            int pzHW = clampi(tz + 1) * HW;
            float* Rs = R + (slot ^ 1) * RSLOT;
#pragma unroll
            for (int j = 0; j < 5; ++j)
                if (sdst[j] >= 0) Rs[sdst[j]] = (simg[j] ? tp : ip)[pzHW + ssrc[j]];
        }

        const float* Rc = R + slot * RSLOT;
        stage_pair(ip, tp, zm, zc, zp, Rc, pa, X);
        if (hasB) stage_pair(ip, tp, zm, zc, zp, Rc, pb, X);
        __syncthreads();

        f4 q[6];
        box3y_pair(X, ty, tx, q);
        __syncthreads();

        int ze = tz - 1;
        if (ze >= z0) {
            f4 v[6];
#pragma unroll
            for (int k = 0; k < 6; ++k) v[k] = A[k] + q[k];

            float mnp = v[0][0], mnt = v[0][1];
            float smp = 0.0f, smt = 0.0f;
#pragma unroll
            for (int c = 0; c < 12; ++c) {
                float pv = v[c >> 1][(c & 1) * 2];
                float tv = v[c >> 1][(c & 1) * 2 + 1];
                mnp = fminf(mnp, pv); smp += pv;
                mnt = fminf(mnt, tv); smt += tv;
            }
            float varp = smp * (1.0f / 12.0f) - mnp;
            float vart = smt * (1.0f / 12.0f) - mnt;
            vsump += varp; vsumt += vart;
            locmnp = fminf(locmnp, varp); locmxp = fmaxf(locmxp, varp);
            locmnt = fminf(locmnt, vart); locmxt = fmaxf(locmxt, vart);

            float invp = -1.0f / varp;   // UNCLIPPED (validated by combo kernel)
            float invt = -1.0f / vart;
            float la = 0.0f;
#pragma unroll
            for (int c = 0; c < 12; ++c) {
                float pv = v[c >> 1][(c & 1) * 2];
                float tv = v[c >> 1][(c & 1) * 2 + 1];
                float ep = __expf((pv - mnp) * invp);
                float et = __expf((tv - mnt) * invt);
                float dd = ep - et;
                la += dd * dd;
            }
            lsum += la;
        }
#pragma unroll
        for (int k = 0; k < 6; ++k) { A[k] = B[k] + q[k]; B[k] = q[k]; }
    }

    block_reduce_atomic(vsump, &acc[0]);
    block_reduce_atomic(vsumt, &acc[1]);
    block_reduce_atomic(lsum,  &acc[2]);
    block_minmax_atomic(locmnp, locmxp, locmnt, locmxt, keys);
}

// ---------------- combo: flag + (fallback recompute) + finalize ----------------

struct SPos {
    int y0, ym, yp;
    int cx[3], cm[3], cp[3];
    int woff;
};

__device__ __forceinline__ SPos make_spos(int p, int y0t, int x0t, int stride) {
    SPos q;
    int py = p >> 4, px = p & 15;
    int gy = clampi(y0t - 1 + py);
    int gx = x0t + px;
    q.y0 = gy * DIM; q.ym = clampi(gy - 2) * DIM; q.yp = clampi(gy + 2) * DIM;
#pragma unroll
    for (int wx = 0; wx < 3; ++wx) {
        int c = clampi(gx + wx - 1);
        q.cx[wx] = c;
        q.cm[wx] = clampi(c - 2);
        q.cp[wx] = clampi(c + 2);
    }
    q.woff = p * stride;
    return q;
}

__device__ __forceinline__ void stage_xsum(const float* __restrict__ im,
                                           int zm, int zc, int zp,
                                           const SPos& q, f4* __restrict__ P) {
    f4 a = (f4)0.0f, b = (f4)0.0f, c = (f4)0.0f;
#pragma unroll
    for (int wx = 0; wx < 3; ++wx) {
        float s0 = im[zm + q.y0 + q.cx[wx]];
        float s1 = im[zc + q.y0 + q.cm[wx]];
        float s2 = im[zc + q.ym + q.cx[wx]];
        float s3 = im[zc + q.y0 + q.cp[wx]];
        float s4 = im[zp + q.y0 + q.cx[wx]];
        float s5 = im[zc + q.yp + q.cx[wx]];
        float d;
        d = s1 - s0; a.x += d * d;
        d = s2 - s0; a.y += d * d;
        d = s2 - s1; a.z += d * d;
        d = s3 - s0; a.w += d * d;
        d = s3 - s2; b.x += d * d;
        d = s4 - s1; b.y += d * d;
        d = s4 - s2; b.z += d * d;
        d = s4 - s3; b.w += d * d;
        d = s5 - s0; c.x += d * d;
        d = s5 - s1; c.y += d * d;
        d = s5 - s3; c.z += d * d;
        d = s5 - s4; c.w += d * d;
    }
    P[q.woff + 0] = a;
    P[q.woff + 1] = b;
    P[q.woff + 2] = c;
}

__device__ __forceinline__ void box3y(const f4* __restrict__ P,
                                      int ty, int tx, f4 q[3]) {
    int base = (ty * TS + tx) * 3;
#pragma unroll
    for (int k = 0; k < 3; ++k)
        q[k] = P[base + k] + P[base + TS * 3 + k] + P[base + 2 * TS * 3 + k];
}

__device__ __forceinline__ float min12(const f4 v[3]) {
    float mn = v[0][0];
#pragma unroll
    for (int i = 0; i < 4; ++i)
        mn = fminf(mn, fminf(v[0][i], fminf(v[1][i], v[2][i])));
    return mn;
}
__device__ __forceinline__ float sum12(const f4 v[3]) {
    float sm = 0.0f;
#pragma unroll
    for (int i = 0; i < 4; ++i)
        sm += v[0][i] + v[1][i] + v[2][i];
    return sm;
}

__global__ __launch_bounds__(256, 4) void combo_kernel(const float* __restrict__ pred,
                                                       const float* __restrict__ targ,
                                                       double* __restrict__ acc,
                                                       unsigned* __restrict__ keys,
                                                       float* __restrict__ out) {
    const float m_p = (float)(acc[0] * (1.0 / (double)NVOX));
    const float m_t = (float)(acc[1] * (1.0 / (double)NVOX));
    const float mnp = fdec(~keys[0]), mxp = fdec(keys[1]);
    const float mnt = fdec(~keys[2]), mxt = fdec(keys[3]);
    const bool clean = (mnp >= m_p * 0.001f) && (mxp <= m_p * 1000.0f) &&
                       (mnt >= m_t * 0.001f) && (mxt <= m_t * 1000.0f);
    if (clean) {
        if (blockIdx.x == 0 && blockIdx.y == 0 && threadIdx.x == 0)
            out[0] = (float)(acc[2] * (1.0 / LOSS_COUNT));
        return;
    }

    // ---- dirty path: full clipped recompute (never taken for these inputs) ----
    __shared__ f4 Xp[NSP * 3];
    __shared__ f4 Xt[NSP * 3];
    const int t = threadIdx.x;
    const int tile = blockIdx.x & 63, n = blockIdx.x >> 6;
    const int x0t = (tile & 7) * TS, y0t = (tile >> 3) * TS;
    const int z0 = blockIdx.y * CHZ;
    const float* ip = pred + (size_t)n * DHW;
    const float* tp = targ + (size_t)n * DHW;

    SPos pa = make_spos(t, y0t, x0t, 3);
    const bool hasB = (t + 256) < NSP;
    SPos pb = make_spos(hasB ? (t + 256) : 0, y0t, x0t, 3);

    const int ty = t >> 4, tx = t & 15;

    f4 Ap[3], Bp[3], At[3], Bt[3];
#pragma unroll
    for (int q = 0; q < 3; ++q) {
        Ap[q] = (f4)0.0f; Bp[q] = (f4)0.0f;
        At[q] = (f4)0.0f; Bt[q] = (f4)0.0f;
    }
    float lsum = 0.0f;

    for (int tz = z0 - 1; tz <= z0 + CHZ; ++tz) {
        int zq = clampi(tz);
        int zc = zq * HW, zm = clampi(zq - 2) * HW, zp = clampi(zq + 2) * HW;
        stage_xsum(ip, zm, zc, zp, pa, Xp);
        stage_xsum(tp, zm, zc, zp, pa, Xt);
        if (hasB) {
            stage_xsum(ip, zm, zc, zp, pb, Xp);
            stage_xsum(tp, zm, zc, zp, pb, Xt);
        }
        __syncthreads();

        f4 qp[3], qt[3];
        box3y(Xp, ty, tx, qp);
        box3y(Xt, ty, tx, qt);
        __syncthreads();

        int ze = tz - 1;
        if (ze >= z0) {
            f4 vp[3], vt[3];
#pragma unroll
            for (int q = 0; q < 3; ++q) {
                vp[q] = Ap[q] + qp[q];
                vt[q] = At[q] + qt[q];
            }
            float mnpv = min12(vp), smp = sum12(vp);
            float mntv = min12(vt), smt = sum12(vt);
            float varp = smp * (1.0f / 12.0f) - mnpv;
            varp = fminf(fmaxf(varp, m_p * 0.001f), m_p * 1000.0f);
            float invp = -1.0f / varp;
            float vart = smt * (1.0f / 12.0f) - mntv;
            vart = fminf(fmaxf(vart, m_t * 0.001f), m_t * 1000.0f);
            float invt = -1.0f / vart;

            float a = 0.0f;
#pragma unroll
            for (int q = 0; q < 3; ++q)
#pragma unroll
                for (int i = 0; i < 4; ++i) {
                    float ep = __expf((vp[q][i] - mnpv) * invp);
                    float et = __expf((vt[q][i] - mntv) * invt);
                    float dd = ep - et;
                    a += dd * dd;
                }
            lsum += a;
        }
#pragma unroll
        for (int q = 0; q < 3; ++q) {
            Ap[q] = Bp[q] + qp[q]; Bp[q] = qp[q];
            At[q] = Bt[q] + qt[q]; Bt[q] = qt[q];
        }
    }

    block_reduce_atomic(lsum, &acc[3]);

    __threadfence();
    if (threadIdx.x == 0) {
        unsigned old = atomicAdd(&keys[6], 1u);
        if (old == TOTAL_BLOCKS - 1u) {
            __threadfence();
            double v = atomicAdd(&acc[3], 0.0);
            out[0] = (float)(v * (1.0 / LOSS_COUNT));
        }
    }
}

extern "C" void kernel_launch(void* const* d_in, const int* in_sizes, int n_in,
                              void* d_out, int out_size, void* d_ws, size_t ws_size,
                              hipStream_t stream) {
    const float* pred = (const float*)d_in[0];
    const float* targ = (const float*)d_in[1];
    float* out = (float*)d_out;
    double* acc = (double*)d_ws;                    // [0]=vsum_p [1]=vsum_t [2]=loss_unclip [3]=loss_clip
    unsigned* keys = (unsigned*)((char*)d_ws + 64); // [0..3]=inv-min/max keys, [6]=fallback ctr

    dim3 block(256);
    dim3 grid(128, 8);   // 64 tiles * 2 batch, 8 z-chunks of 16

    hipMemsetAsync(d_ws, 0, 256, stream);  // all-zero init (inverted min keys)
    fused_kernel<<<grid, block, 0, stream>>>(pred, targ, acc, keys);
    combo_kernel<<<grid, block, 0, stream>>>(pred, targ, acc, keys, out);
}